// Round 10
// baseline (301.151 us; speedup 1.0000x reference)
//
#include <hip/hip_runtime.h>

#define N_NODES 150000
#define N_EDGES 2400000
#define D 32
#define NBUCK 1172                 // ceil(N/128)
#define CHUNK 4096
#define NCHK 586                   // ceil(E/CHUNK)
#define CSR_CAP (N_EDGES + 3 * N_NODES + 64)

// ---------- pass A: per-chunk LDS histogram of buckets ----------
__global__ __launch_bounds__(256) void kA_hist(const int* __restrict__ dst,
                                               int* __restrict__ cnt) {
    __shared__ int bins[NBUCK];
    int t = threadIdx.x;
    for (int k = t; k < NBUCK; k += 256) bins[k] = 0;
    __syncthreads();
    int e0 = blockIdx.x * CHUNK;
#pragma unroll
    for (int r = 0; r < CHUNK / 256; ++r) {
        int e = e0 + r * 256 + t;
        if (e < N_EDGES) atomicAdd(&bins[dst[e] >> 7], 1);
    }
    __syncthreads();
    for (int k = t; k < NBUCK; k += 256) cnt[blockIdx.x * NBUCK + k] = bins[k];
}

// ---------- S1: per-bucket exclusive scan over chunks ----------
__global__ __launch_bounds__(256) void kS1(int* __restrict__ cnt, int* __restrict__ bstart) {
    __shared__ int tile[8][33];
    __shared__ int carry[32];
    int t = threadIdx.x;
    int tl = t & 31, tr = t >> 5;
    int b = blockIdx.x * 32 + tl;
    if (t < 32) carry[t] = 0;
    __syncthreads();
    for (int c0 = 0; c0 < NCHK; c0 += 8) {
        int c = c0 + tr;
        int v = (c < NCHK && b < NBUCK) ? cnt[c * NBUCK + b] : 0;
        tile[tr][tl] = v;
        __syncthreads();
        if (t < 32) {
            int s = carry[t];
#pragma unroll
            for (int r = 0; r < 8; ++r) { int x = tile[r][t]; tile[r][t] = s; s += x; }
            carry[t] = s;
        }
        __syncthreads();
        if (c < NCHK && b < NBUCK) cnt[c * NBUCK + b] = tile[tr][tl];
        __syncthreads();
    }
    if (t < 32 && b < NBUCK) bstart[b] = carry[t];
}

// ---------- single-block exclusive scan in place; a[m] = total ----------
__global__ void k_scan_small(int* __restrict__ a, int m) {
    __shared__ int s[256];
    __shared__ int carry;
    int t = threadIdx.x;
    if (t == 0) carry = 0;
    __syncthreads();
    for (int base = 0; base < m; base += 256) {
        int v = (base + t < m) ? a[base + t] : 0;
        s[t] = v;
        __syncthreads();
        for (int off = 1; off < 256; off <<= 1) {
            int add = (t >= off) ? s[t - off] : 0;
            __syncthreads();
            s[t] += add;
            __syncthreads();
        }
        int c0 = carry;
        if (base + t < m) a[base + t] = c0 + s[t] - v;
        int bsum = s[255];
        __syncthreads();
        if (t == 0) carry = c0 + bsum;
        __syncthreads();
    }
    if (t == 0) a[m] = carry;
}

// ---------- pass B: scatter packed edges into bucket-grouped ebuf ----------
__global__ __launch_bounds__(256) void kB_scatter(const int* __restrict__ src,
                                                  const int* __restrict__ dst,
                                                  const int* __restrict__ cnt,
                                                  const int* __restrict__ bstart,
                                                  int* __restrict__ ebuf) {
    __shared__ int lofs[NBUCK];
    int t = threadIdx.x;
    for (int k = t; k < NBUCK; k += 256)
        lofs[k] = bstart[k] + cnt[blockIdx.x * NBUCK + k];
    __syncthreads();
    int e0 = blockIdx.x * CHUNK;
#pragma unroll
    for (int r = 0; r < CHUNK / 256; ++r) {
        int e = e0 + r * 256 + t;
        if (e < N_EDGES) {
            int d = dst[e];
            int p = atomicAdd(&lofs[d >> 7], 1);
            ebuf[p] = src[e] | ((d & 127) << 18);  // src < 2^18
        }
    }
}

// ---------- C1: per-bucket degree histogram -> deg, dis, xd, padded totals ----------
__global__ __launch_bounds__(256) void kC1(const int* __restrict__ ebuf,
                                           const int* __restrict__ bstart,
                                           const float2* __restrict__ x,
                                           int* __restrict__ deg,
                                           float* __restrict__ dis,
                                           float4* __restrict__ xd,
                                           int* __restrict__ pbase) {
    __shared__ int hist[128];
    __shared__ int sc[128];
    int b = blockIdx.x, t = threadIdx.x;
    if (t < 128) hist[t] = 0;
    __syncthreads();
    int s0 = bstart[b], s1 = bstart[b + 1];
    for (int e = s0 + t; e < s1; e += 256) atomicAdd(&hist[ebuf[e] >> 18], 1);
    __syncthreads();
    int i = b * 128 + t;
    if (t < 128) {
        int dv = hist[t];
        if (i < N_NODES) {
            deg[i] = dv;
            float dz = rsqrtf((float)dv + 1.0f);
            dis[i] = dz;
            float2 xv = x[i];
            xd[i] = make_float4(xv.x, xv.y, dz, 0.f);
        } else if (i == N_NODES) {
            xd[i] = make_float4(0.f, 0.f, 0.f, 0.f);
        }
        sc[t] = (i < N_NODES) ? ((dv + 3) & ~3) : 0;  // pad-4
    }
    __syncthreads();
    for (int s = 64; s > 0; s >>= 1) {
        if (t < s) sc[t] += sc[t + s];
        __syncthreads();
    }
    if (t == 0) pbase[b] = sc[0];
}

// ---------- C3: per-bucket CSR fill (pad-4 rows) + irow + slack + zero rows ----------
__global__ __launch_bounds__(256) void kC3(const int* __restrict__ ebuf,
                                           const int* __restrict__ bstart,
                                           const int* __restrict__ deg,
                                           const int* __restrict__ pbase,
                                           int* __restrict__ csr,
                                           int* __restrict__ irow,
                                           float* __restrict__ HA,
                                           float* __restrict__ HB) {
    __shared__ int sc[128];
    __shared__ int loff[128];
    __shared__ int pos[128];
    int b = blockIdx.x, t = threadIdx.x;
    if (b == 0) {
        if (t == 0) irow[N_NODES] = pbase[NBUCK];
        if (t < 64) csr[pbase[NBUCK] + t] = N_NODES;  // slack for 16-wide reads + prefetch
        if (t >= 64 && t < 96) HA[(size_t)N_NODES * D + (t - 64)] = 0.f;   // zero row
        if (t >= 96 && t < 128) HB[(size_t)N_NODES * D + (t - 96)] = 0.f;  // zero row
    }
    int i = b * 128 + t;
    int dv = 0, pad = 0;
    if (t < 128) {
        dv = (i < N_NODES) ? deg[i] : 0;
        pad = (dv + 3) & ~3;
        sc[t] = pad;
        pos[t] = 0;
    }
    __syncthreads();
    for (int off = 1; off < 128; off <<= 1) {
        int add = 0;
        if (t < 128 && t >= off) add = sc[t - off];
        __syncthreads();
        if (t < 128) sc[t] += add;
        __syncthreads();
    }
    int base = pbase[b];
    if (t < 128) {
        loff[t] = sc[t] - pad;  // exclusive prefix
        if (i < N_NODES) irow[i] = base + loff[t];
    }
    __syncthreads();
    int s0 = bstart[b], s1 = bstart[b + 1];
    for (int e = s0 + t; e < s1; e += 256) {
        int v = ebuf[e];
        int dl = v >> 18;
        int p = atomicAdd(&pos[dl], 1);
        csr[base + loff[dl] + p] = v & 0x3FFFF;
    }
    __syncthreads();
    if (t < 128 && i < N_NODES) {
        int st = base + loff[t] + dv, en = base + loff[t] + pad;
        for (int q = st; q < en; ++q) csr[q] = N_NODES;  // pad -> zero row
    }
}

// ---------- layer1 fused with fc1: 2-node LDS-staged gather + broadcast MLP ----------
__global__ __launch_bounds__(256) void k_layer1f(const float4* __restrict__ xd,
                                                 const int* __restrict__ row,
                                                 const int* __restrict__ csr,
                                                 const float* __restrict__ W,   // fc1_w [2][32]
                                                 const float* __restrict__ bf,  // fc1_b
                                                 const float* __restrict__ Wc,  // conv1_w
                                                 const float* __restrict__ bc,  // conv1_b
                                                 float* __restrict__ hout) {
    __shared__ float4 stage[8][2][16];
    __shared__ float arow[16][32];
    int g = threadIdx.x >> 5, l = threadIdx.x & 31, f = l;
    int gg = blockIdx.x * 8 + g;
    int iA = gg * 2, iB = iA + 1;  // 9375*8*2 == 150000, exact grid
    float w0 = W[f], w1 = W[D + f], bb = bf[f];
    float4 svA = xd[iA], svB = xd[iB];
    float hsA = fmaf(svA.x, w0, fmaf(svA.y, w1, bb)); hsA = hsA > 0.f ? hsA : 0.f;
    float hsB = fmaf(svB.x, w0, fmaf(svB.y, w1, bb)); hsB = hsB > 0.f ? hsB : 0.f;
    float aA = hsA * svA.z, aB = hsB * svB.z;  // self-loop terms
    int rsA = row[iA], mid = row[iB], reB = row[iB + 1];
    int jA = rsA, jB = mid;
    int half = l >> 4, li = l & 15;
    int mye = half ? reB : mid;
    int slot0 = (half ? jB : jA) + li;
    int cs = csr[slot0];
    cs = (slot0 < mye) ? cs : N_NODES;
    while (jA < mid || jB < reB) {
        stage[g][half][li] = xd[cs];  // 32 rows staged in one instruction
        int nslot = (half ? jB : jA) + 16 + li;
        int ncs = csr[nslot];                    // slack-safe read
        ncs = (nslot < mye) ? ncs : N_NODES;     // value sanitize
        if (jA < mid) {
#pragma unroll
            for (int it = 0; it < 4; ++it) {
                if (jA + it * 4 < mid) {
                    float4 v0 = stage[g][0][it * 4 + 0];
                    float4 v1 = stage[g][0][it * 4 + 1];
                    float4 v2 = stage[g][0][it * 4 + 2];
                    float4 v3 = stage[g][0][it * 4 + 3];
                    float h0 = fmaf(v0.x, w0, fmaf(v0.y, w1, bb)); h0 = h0 > 0.f ? h0 : 0.f;
                    float h1 = fmaf(v1.x, w0, fmaf(v1.y, w1, bb)); h1 = h1 > 0.f ? h1 : 0.f;
                    float h2 = fmaf(v2.x, w0, fmaf(v2.y, w1, bb)); h2 = h2 > 0.f ? h2 : 0.f;
                    float h3 = fmaf(v3.x, w0, fmaf(v3.y, w1, bb)); h3 = h3 > 0.f ? h3 : 0.f;
                    aA = fmaf(h0, v0.z, aA); aA = fmaf(h1, v1.z, aA);
                    aA = fmaf(h2, v2.z, aA); aA = fmaf(h3, v3.z, aA);
                }
            }
            jA += 16;
        }
        if (jB < reB) {
#pragma unroll
            for (int it = 0; it < 4; ++it) {
                if (jB + it * 4 < reB) {
                    float4 v0 = stage[g][1][it * 4 + 0];
                    float4 v1 = stage[g][1][it * 4 + 1];
                    float4 v2 = stage[g][1][it * 4 + 2];
                    float4 v3 = stage[g][1][it * 4 + 3];
                    float h0 = fmaf(v0.x, w0, fmaf(v0.y, w1, bb)); h0 = h0 > 0.f ? h0 : 0.f;
                    float h1 = fmaf(v1.x, w0, fmaf(v1.y, w1, bb)); h1 = h1 > 0.f ? h1 : 0.f;
                    float h2 = fmaf(v2.x, w0, fmaf(v2.y, w1, bb)); h2 = h2 > 0.f ? h2 : 0.f;
                    float h3 = fmaf(v3.x, w0, fmaf(v3.y, w1, bb)); h3 = h3 > 0.f ? h3 : 0.f;
                    aB = fmaf(h0, v0.z, aB); aB = fmaf(h1, v1.z, aB);
                    aB = fmaf(h2, v2.z, aB); aB = fmaf(h3, v3.z, aB);
                }
            }
            jB += 16;
        }
        cs = ncs;
    }
    aA *= svA.z; aB *= svB.z;
    arow[g * 2][f] = aA;
    arow[g * 2 + 1][f] = aB;
    float accA = 0.f, accB = 0.f;
#pragma unroll
    for (int q = 0; q < 8; ++q) {
        float4 qa = ((const float4*)arow[g * 2])[q];
        float4 qb = ((const float4*)arow[g * 2 + 1])[q];
        float wq0 = Wc[(4 * q + 0) * D + f], wq1 = Wc[(4 * q + 1) * D + f];
        float wq2 = Wc[(4 * q + 2) * D + f], wq3 = Wc[(4 * q + 3) * D + f];
        accA = fmaf(qa.x, wq0, fmaf(qa.y, wq1, fmaf(qa.z, wq2, fmaf(qa.w, wq3, accA))));
        accB = fmaf(qb.x, wq0, fmaf(qb.y, wq1, fmaf(qb.z, wq2, fmaf(qb.w, wq3, accB))));
    }
    float bcf = bc[f];
    float vA = accA + bcf; vA = vA > 0.f ? vA : 0.f;
    float vB = accB + bcf; vB = vB > 0.f ? vB : 0.f;
    hout[iA * D + f] = vA * svA.z;
    hout[iB * D + f] = vB * svB.z;
}

// ---------- gather helpers for 4-node kernels ----------
#define GATHER4_LOADS(jN, eN, csN, nN, vN)                                        \
    if (jN < eN) {                                                                \
        nN = csr[jN + 16 + l16];                                                  \
        _Pragma("unroll")                                                         \
        for (int it = 0; it < 4; ++it)                                            \
            if (jN + it * 4 < eN) {                                               \
                int s = __shfl(csN, it * 4 + sub, 32);                            \
                vN[it] = rowf4[s * 8 + c];                                        \
            }                                                                     \
    }

#define GATHER4_ACC(jN, eN, csN, nN, vN, aN)                                      \
    if (jN < eN) {                                                                \
        _Pragma("unroll")                                                         \
        for (int it = 0; it < 4; ++it)                                            \
            if (jN + it * 4 < eN) {                                               \
                aN.x += vN[it].x; aN.y += vN[it].y;                               \
                aN.z += vN[it].z; aN.w += vN[it].w;                               \
            }                                                                     \
        csN = nN; jN += 16;                                                       \
    }

#define XORRED(aN)                                                                \
    aN.x += __shfl_xor(aN.x, 8, 32);  aN.y += __shfl_xor(aN.y, 8, 32);            \
    aN.z += __shfl_xor(aN.z, 8, 32);  aN.w += __shfl_xor(aN.w, 8, 32);            \
    aN.x += __shfl_xor(aN.x, 16, 32); aN.y += __shfl_xor(aN.y, 16, 32);           \
    aN.z += __shfl_xor(aN.z, 16, 32); aN.w += __shfl_xor(aN.w, 16, 32);

// ---------- fused layer: 4-node batched gather (16 rows in flight) + transform ----------
__global__ __launch_bounds__(256) void k_layer(const float* __restrict__ hsc,
                                               const int* __restrict__ row,
                                               const int* __restrict__ csr,
                                               const float* __restrict__ dis,
                                               const float* __restrict__ W,
                                               const float* __restrict__ b,
                                               float* __restrict__ hout) {
    __shared__ float arow[32][32];
    int g = threadIdx.x >> 5, l = threadIdx.x & 31, f = l;
    int gg = blockIdx.x * 8 + g;
    int i0 = gg * 4;
    if (i0 >= N_NODES) return;
    int c = l & 7, l16 = l & 15, sub = l >> 3;
    const float4* rowf4 = (const float4*)hsc;
    int r0 = row[i0], r1 = row[i0 + 1], r2 = row[i0 + 2], r3 = row[i0 + 3], r4 = row[i0 + 4];
    int j0 = r0, e0 = r1, j1 = r1, e1 = r2, j2 = r2, e2 = r3, j3 = r3, e3 = r4;
    float4 a0 = make_float4(0.f, 0.f, 0.f, 0.f), a1 = a0, a2 = a0, a3 = a0;
    int cs0 = csr[j0 + l16], cs1 = csr[j1 + l16], cs2 = csr[j2 + l16], cs3 = csr[j3 + l16];
    while (j0 < e0 || j1 < e1 || j2 < e2 || j3 < e3) {
        int n0, n1, n2, n3;
        float4 v0[4], v1[4], v2[4], v3[4];
        GATHER4_LOADS(j0, e0, cs0, n0, v0)
        GATHER4_LOADS(j1, e1, cs1, n1, v1)
        GATHER4_LOADS(j2, e2, cs2, n2, v2)
        GATHER4_LOADS(j3, e3, cs3, n3, v3)
        GATHER4_ACC(j0, e0, cs0, n0, v0, a0)
        GATHER4_ACC(j1, e1, cs1, n1, v1, a1)
        GATHER4_ACC(j2, e2, cs2, n2, v2, a2)
        GATHER4_ACC(j3, e3, cs3, n3, v3, a3)
    }
    XORRED(a0) XORRED(a1) XORRED(a2) XORRED(a3)
    float di0 = dis[i0], di1 = dis[i0 + 1], di2 = dis[i0 + 2], di3 = dis[i0 + 3];
    float4 s0 = rowf4[(i0 + 0) * 8 + c], s1 = rowf4[(i0 + 1) * 8 + c];
    float4 s2 = rowf4[(i0 + 2) * 8 + c], s3 = rowf4[(i0 + 3) * 8 + c];
    a0.x = (a0.x + s0.x) * di0; a0.y = (a0.y + s0.y) * di0; a0.z = (a0.z + s0.z) * di0; a0.w = (a0.w + s0.w) * di0;
    a1.x = (a1.x + s1.x) * di1; a1.y = (a1.y + s1.y) * di1; a1.z = (a1.z + s1.z) * di1; a1.w = (a1.w + s1.w) * di1;
    a2.x = (a2.x + s2.x) * di2; a2.y = (a2.y + s2.y) * di2; a2.z = (a2.z + s2.z) * di2; a2.w = (a2.w + s2.w) * di2;
    a3.x = (a3.x + s3.x) * di3; a3.y = (a3.y + s3.y) * di3; a3.z = (a3.z + s3.z) * di3; a3.w = (a3.w + s3.w) * di3;
    int wn = l >> 3;
    float4 wsel = wn == 0 ? a0 : wn == 1 ? a1 : wn == 2 ? a2 : a3;
    ((float4*)arow[g * 4 + wn])[l & 7] = wsel;  // uniform bank spread
    float acc0 = 0.f, acc1 = 0.f, acc2 = 0.f, acc3 = 0.f;
#pragma unroll
    for (int q = 0; q < 8; ++q) {
        float4 qa0 = ((const float4*)arow[g * 4 + 0])[q];
        float4 qa1 = ((const float4*)arow[g * 4 + 1])[q];
        float4 qa2 = ((const float4*)arow[g * 4 + 2])[q];
        float4 qa3 = ((const float4*)arow[g * 4 + 3])[q];
        float wq0 = W[(4 * q + 0) * D + f], wq1 = W[(4 * q + 1) * D + f];
        float wq2 = W[(4 * q + 2) * D + f], wq3 = W[(4 * q + 3) * D + f];
        acc0 = fmaf(qa0.x, wq0, fmaf(qa0.y, wq1, fmaf(qa0.z, wq2, fmaf(qa0.w, wq3, acc0))));
        acc1 = fmaf(qa1.x, wq0, fmaf(qa1.y, wq1, fmaf(qa1.z, wq2, fmaf(qa1.w, wq3, acc1))));
        acc2 = fmaf(qa2.x, wq0, fmaf(qa2.y, wq1, fmaf(qa2.z, wq2, fmaf(qa2.w, wq3, acc2))));
        acc3 = fmaf(qa3.x, wq0, fmaf(qa3.y, wq1, fmaf(qa3.z, wq2, fmaf(qa3.w, wq3, acc3))));
    }
    float bb = b[f];
    float o0 = acc0 + bb; o0 = o0 > 0.f ? o0 : 0.f;
    float o1 = acc1 + bb; o1 = o1 > 0.f ? o1 : 0.f;
    float o2 = acc2 + bb; o2 = o2 > 0.f ? o2 : 0.f;
    float o3 = acc3 + bb; o3 = o3 > 0.f ? o3 : 0.f;
    hout[(i0 + 0) * D + f] = o0 * di0;
    hout[(i0 + 1) * D + f] = o1 * di1;
    hout[(i0 + 2) * D + f] = o2 * di2;
    hout[(i0 + 3) * D + f] = o3 * di3;
}

// ---------- heads: 4-node batched gather, two transforms + 32->1 dots ----------
__global__ __launch_bounds__(256) void k_heads(
    const float* __restrict__ hsc, const int* __restrict__ row,
    const int* __restrict__ csr, const float* __restrict__ dis,
    const float* __restrict__ W1, const float* __restrict__ b1,
    const float* __restrict__ W2, const float* __restrict__ b2,
    const float* __restrict__ fw1, const float* __restrict__ fb1,
    const float* __restrict__ fw2, const float* __restrict__ fb2,
    float* __restrict__ out) {
    __shared__ float arow[32][32];
    int g = threadIdx.x >> 5, l = threadIdx.x & 31, f = l;
    int gg = blockIdx.x * 8 + g;
    int i0 = gg * 4;
    if (i0 >= N_NODES) return;
    int c = l & 7, l16 = l & 15, sub = l >> 3;
    const float4* rowf4 = (const float4*)hsc;
    int r0 = row[i0], r1 = row[i0 + 1], r2 = row[i0 + 2], r3 = row[i0 + 3], r4 = row[i0 + 4];
    int j0 = r0, e0 = r1, j1 = r1, e1 = r2, j2 = r2, e2 = r3, j3 = r3, e3 = r4;
    float4 a0 = make_float4(0.f, 0.f, 0.f, 0.f), a1 = a0, a2 = a0, a3 = a0;
    int cs0 = csr[j0 + l16], cs1 = csr[j1 + l16], cs2 = csr[j2 + l16], cs3 = csr[j3 + l16];
    while (j0 < e0 || j1 < e1 || j2 < e2 || j3 < e3) {
        int n0, n1, n2, n3;
        float4 v0[4], v1[4], v2[4], v3[4];
        GATHER4_LOADS(j0, e0, cs0, n0, v0)
        GATHER4_LOADS(j1, e1, cs1, n1, v1)
        GATHER4_LOADS(j2, e2, cs2, n2, v2)
        GATHER4_LOADS(j3, e3, cs3, n3, v3)
        GATHER4_ACC(j0, e0, cs0, n0, v0, a0)
        GATHER4_ACC(j1, e1, cs1, n1, v1, a1)
        GATHER4_ACC(j2, e2, cs2, n2, v2, a2)
        GATHER4_ACC(j3, e3, cs3, n3, v3, a3)
    }
    XORRED(a0) XORRED(a1) XORRED(a2) XORRED(a3)
    float di0 = dis[i0], di1 = dis[i0 + 1], di2 = dis[i0 + 2], di3 = dis[i0 + 3];
    float4 s0 = rowf4[(i0 + 0) * 8 + c], s1 = rowf4[(i0 + 1) * 8 + c];
    float4 s2 = rowf4[(i0 + 2) * 8 + c], s3 = rowf4[(i0 + 3) * 8 + c];
    a0.x = (a0.x + s0.x) * di0; a0.y = (a0.y + s0.y) * di0; a0.z = (a0.z + s0.z) * di0; a0.w = (a0.w + s0.w) * di0;
    a1.x = (a1.x + s1.x) * di1; a1.y = (a1.y + s1.y) * di1; a1.z = (a1.z + s1.z) * di1; a1.w = (a1.w + s1.w) * di1;
    a2.x = (a2.x + s2.x) * di2; a2.y = (a2.y + s2.y) * di2; a2.z = (a2.z + s2.z) * di2; a2.w = (a2.w + s2.w) * di2;
    a3.x = (a3.x + s3.x) * di3; a3.y = (a3.y + s3.y) * di3; a3.z = (a3.z + s3.z) * di3; a3.w = (a3.w + s3.w) * di3;
    int wn = l >> 3;
    float4 wsel = wn == 0 ? a0 : wn == 1 ? a1 : wn == 2 ? a2 : a3;
    ((float4*)arow[g * 4 + wn])[l & 7] = wsel;
    float h10 = 0.f, h11 = 0.f, h12 = 0.f, h13 = 0.f;
    float h20 = 0.f, h21 = 0.f, h22 = 0.f, h23 = 0.f;
#pragma unroll
    for (int q = 0; q < 8; ++q) {
        float4 qa0 = ((const float4*)arow[g * 4 + 0])[q];
        float4 qa1 = ((const float4*)arow[g * 4 + 1])[q];
        float4 qa2 = ((const float4*)arow[g * 4 + 2])[q];
        float4 qa3 = ((const float4*)arow[g * 4 + 3])[q];
        float u0 = W1[(4 * q + 0) * D + f], u1 = W1[(4 * q + 1) * D + f];
        float u2 = W1[(4 * q + 2) * D + f], u3 = W1[(4 * q + 3) * D + f];
        float t0 = W2[(4 * q + 0) * D + f], t1 = W2[(4 * q + 1) * D + f];
        float t2 = W2[(4 * q + 2) * D + f], t3 = W2[(4 * q + 3) * D + f];
        h10 = fmaf(qa0.x, u0, fmaf(qa0.y, u1, fmaf(qa0.z, u2, fmaf(qa0.w, u3, h10))));
        h11 = fmaf(qa1.x, u0, fmaf(qa1.y, u1, fmaf(qa1.z, u2, fmaf(qa1.w, u3, h11))));
        h12 = fmaf(qa2.x, u0, fmaf(qa2.y, u1, fmaf(qa2.z, u2, fmaf(qa2.w, u3, h12))));
        h13 = fmaf(qa3.x, u0, fmaf(qa3.y, u1, fmaf(qa3.z, u2, fmaf(qa3.w, u3, h13))));
        h20 = fmaf(qa0.x, t0, fmaf(qa0.y, t1, fmaf(qa0.z, t2, fmaf(qa0.w, t3, h20))));
        h21 = fmaf(qa1.x, t0, fmaf(qa1.y, t1, fmaf(qa1.z, t2, fmaf(qa1.w, t3, h21))));
        h22 = fmaf(qa2.x, t0, fmaf(qa2.y, t1, fmaf(qa2.z, t2, fmaf(qa2.w, t3, h22))));
        h23 = fmaf(qa3.x, t0, fmaf(qa3.y, t1, fmaf(qa3.z, t2, fmaf(qa3.w, t3, h23))));
    }
    float b1f = b1[f], b2f = b2[f], g1 = fw1[f], g2 = fw2[f];
    float v10 = h10 + b1f; v10 = (v10 > 0.f ? v10 : 0.f) * g1;
    float v11 = h11 + b1f; v11 = (v11 > 0.f ? v11 : 0.f) * g1;
    float v12 = h12 + b1f; v12 = (v12 > 0.f ? v12 : 0.f) * g1;
    float v13 = h13 + b1f; v13 = (v13 > 0.f ? v13 : 0.f) * g1;
    float v20 = h20 + b2f; v20 = (v20 > 0.f ? v20 : 0.f) * g2;
    float v21 = h21 + b2f; v21 = (v21 > 0.f ? v21 : 0.f) * g2;
    float v22 = h22 + b2f; v22 = (v22 > 0.f ? v22 : 0.f) * g2;
    float v23 = h23 + b2f; v23 = (v23 > 0.f ? v23 : 0.f) * g2;
#pragma unroll
    for (int o = 16; o > 0; o >>= 1) {
        v10 += __shfl_down(v10, o, 32); v11 += __shfl_down(v11, o, 32);
        v12 += __shfl_down(v12, o, 32); v13 += __shfl_down(v13, o, 32);
        v20 += __shfl_down(v20, o, 32); v21 += __shfl_down(v21, o, 32);
        v22 += __shfl_down(v22, o, 32); v23 += __shfl_down(v23, o, 32);
    }
    if (l == 0) {
        float fb1v = fb1[0], fb2v = fb2[0];
        float4 oA = make_float4(v10 + fb1v, v20 + fb2v, v11 + fb1v, v21 + fb2v);
        float4 oB = make_float4(v12 + fb1v, v22 + fb2v, v13 + fb1v, v23 + fb2v);
        *(float4*)&out[i0 * 2] = oA;
        *(float4*)&out[i0 * 2 + 4] = oB;
    }
}

extern "C" void kernel_launch(void* const* d_in, const int* in_sizes, int n_in,
                              void* d_out, int out_size, void* d_ws, size_t ws_size,
                              hipStream_t stream) {
    const float* x       = (const float*)d_in[0];
    const int*   eidx    = (const int*)d_in[1];
    const float* fc1_w   = (const float*)d_in[2];
    const float* fc1_b   = (const float*)d_in[3];
    const float* conv1_w = (const float*)d_in[4];
    const float* conv1_b = (const float*)d_in[5];
    const float* conv2_w = (const float*)d_in[6];
    const float* conv2_b = (const float*)d_in[7];
    const float* c31_w   = (const float*)d_in[8];
    const float* c31_b   = (const float*)d_in[9];
    const float* c32_w   = (const float*)d_in[10];
    const float* c32_b   = (const float*)d_in[11];
    const float* fc21_w  = (const float*)d_in[12];
    const float* fc21_b  = (const float*)d_in[13];
    const float* fc22_w  = (const float*)d_in[14];
    const float* fc22_b  = (const float*)d_in[15];
    float* out = (float*)d_out;

    const int* src = eidx;            // edge_index[0]
    const int* dst = eidx + N_EDGES;  // edge_index[1]

    // ----- workspace layout (int units; 16B alignment preserved) -----
    int*   wsb    = (int*)d_ws;
    int*   csr    = wsb;                        // CSR_CAP
    int*   irow   = wsb + 2850064;              // 150,004
    int*   bstart = wsb + 3000068;              // 1,174
    int*   pbase  = wsb + 3001242;              // 1,174
    float* dis    = (float*)(wsb + 3002416);    // 150,000
    float* HA     = (float*)(wsb + 3152416);    // 4,800,032 floats
    float* HB     = (float*)(wsb + 7952448);    // 4,800,032 floats
    // transient aliases inside HA (dead before k_layer writes HA):
    int*    cnt  = (int*)HA;                    // 686,792
    int*    ebuf = (int*)HA + 700000;           // 2,400,000
    float4* xd   = (float4*)((int*)HA + 3100016);  // (N+1) float4
    // deg aliases HB low (dead before k_layer1f writes HB):
    int*    deg  = (int*)HB;                    // 150,000

    const int BLK = 256;
    const int gL1 = N_NODES / 16;                   // 9375 (2-node layer1f, exact)
    const int gL4 = (N_NODES / 4 + 7) / 8;          // 4688 (4-node kernels)

    // ----- CSR build (no global atomics) -----
    kA_hist<<<NCHK, BLK, 0, stream>>>(dst, cnt);
    kS1<<<(NBUCK + 31) / 32, BLK, 0, stream>>>(cnt, bstart);
    k_scan_small<<<1, BLK, 0, stream>>>(bstart, NBUCK);
    kB_scatter<<<NCHK, BLK, 0, stream>>>(src, dst, cnt, bstart, ebuf);
    kC1<<<NBUCK, BLK, 0, stream>>>(ebuf, bstart, (const float2*)x, deg, dis, xd, pbase);
    k_scan_small<<<1, BLK, 0, stream>>>(pbase, NBUCK);
    kC3<<<NBUCK, BLK, 0, stream>>>(ebuf, bstart, deg, pbase, csr, irow, HA, HB);

    // ----- network -----
    k_layer1f<<<gL1, BLK, 0, stream>>>(xd, irow, csr, fc1_w, fc1_b, conv1_w, conv1_b, HB);
    k_layer<<<gL4, BLK, 0, stream>>>(HB, irow, csr, dis, conv2_w, conv2_b, HA);
    k_heads<<<gL4, BLK, 0, stream>>>(HA, irow, csr, dis, c31_w, c31_b, c32_w, c32_b,
                                     fc21_w, fc21_b, fc22_w, fc22_b, out);
}